// Round 1
// baseline (415.471 us; speedup 1.0000x reference)
//
#include <hip/hip_runtime.h>
#include <hip/hip_bf16.h>

typedef unsigned int u32;
typedef unsigned short u16;
typedef __attribute__((ext_vector_type(8))) short short8;
typedef __attribute__((ext_vector_type(4))) float f32x4;

#define EPSV 1e-5f
#define MAXN (1.0f - 1e-5f)
#define THETA 0.17f
#define CAP 512

__device__ __forceinline__ u16 f2bf(float f) {
    union { float f; u32 u; } v; v.f = f;
    u32 u = v.u;
    u32 r = (u + 0x7fffu + ((u >> 16) & 1u)) >> 16;
    return (u16)r;
}
__device__ __forceinline__ float bf2f(u16 h) {
    union { u32 u; float f; } v; v.u = ((u32)h) << 16;
    return v.f;
}

// ---------------- zero counters ----------------
__global__ __launch_bounds__(256) void k_zero(u32* p, int n) {
    int i = blockIdx.x * 256 + threadIdx.x;
    if (i < n) p[i] = 0;
}

// ---------------- memory bank: project + bf16 + y2 ----------------
__global__ __launch_bounds__(256) void k_mem(const float* __restrict__ mem,
                                             u16* __restrict__ mbf,
                                             float* __restrict__ y2m) {
    const int row = blockIdx.x * 4 + (threadIdx.x >> 6);
    const int lane = threadIdx.x & 63;
    const float4* p = (const float4*)(mem + (size_t)row * 256);
    float4 v = p[lane];
    float ss = v.x * v.x + v.y * v.y + v.z * v.z + v.w * v.w;
#pragma unroll
    for (int off = 32; off; off >>= 1) ss += __shfl_xor(ss, off);
    float norm = sqrtf(ss);
    float scale = (norm > MAXN) ? MAXN / fmaxf(norm, EPSV) : 1.0f;
    float a = v.x * scale, b = v.y * scale, c = v.z * scale, d = v.w * scale;
    float s2 = a * a + b * b + c * c + d * d;
#pragma unroll
    for (int off = 32; off; off >>= 1) s2 += __shfl_xor(s2, off);
    ushort4 u; u.x = f2bf(a); u.y = f2bf(b); u.z = f2bf(c); u.w = f2bf(d);
    *(ushort4*)&mbf[(size_t)row * 256 + lane * 4] = u;
    if (lane == 0) y2m[row] = s2;
}

// ---------------- f32 -> bf16 convert (x4 per thread) ----------------
__global__ __launch_bounds__(256) void k_conv4(const float* __restrict__ in,
                                               u16* __restrict__ out, int n4) {
    int i = blockIdx.x * 256 + threadIdx.x;
    if (i < n4) {
        float4 v = ((const float4*)in)[i];
        ushort4 u; u.x = f2bf(v.x); u.y = f2bf(v.y); u.z = f2bf(v.z); u.w = f2bf(v.w);
        ((ushort4*)out)[i] = u;
    }
}

// ---------------- transpose + convert: out[n*K+k] = bf16(in[k*N+n]) ----------------
__global__ __launch_bounds__(256) void k_tr(const float* __restrict__ in,
                                            u16* __restrict__ out, int K, int N) {
    int idx = blockIdx.x * 256 + threadIdx.x;
    if (idx < K * N) {
        int nn = idx / K;
        int kk = idx - nn * K;
        out[idx] = f2bf(in[(size_t)kk * N + nn]);
    }
}

// ---------------- GEMM1 (2048x1024x256) + bias + LayerNorm + GELU -> qg bf16 ----------------
// block: 16 q rows x full 256 cols; 4 waves, wave w covers cols [64w,64w+64)
__global__ __launch_bounds__(256) void k_g1(const u16* __restrict__ hb,
                                            const u16* __restrict__ w1t,
                                            const float* __restrict__ b1,
                                            const float* __restrict__ lng,
                                            const float* __restrict__ lnb,
                                            u16* __restrict__ qg) {
    __shared__ float sm[16 * 260];
    const int t = threadIdx.x;
    const int w = t >> 6, lane = t & 63;
    const int l16 = lane & 15, kq = (lane >> 4) * 8, rbase = (lane >> 4) * 4;
    const int q0 = blockIdx.x * 16;
    f32x4 zero = {0.f, 0.f, 0.f, 0.f};
    f32x4 acc[4] = {zero, zero, zero, zero};
    const u16* ap = hb + (size_t)(q0 + l16) * 1024 + kq;
    for (int k0 = 0; k0 < 1024; k0 += 32) {
        short8 av = *(const short8*)(ap + k0);
#pragma unroll
        for (int ct = 0; ct < 4; ++ct) {
            int n = w * 64 + ct * 16 + l16;
            short8 bv = *(const short8*)&w1t[(size_t)n * 1024 + k0 + kq];
            acc[ct] = __builtin_amdgcn_mfma_f32_16x16x32_bf16(av, bv, acc[ct], 0, 0, 0);
        }
    }
#pragma unroll
    for (int ct = 0; ct < 4; ++ct) {
        int n = w * 64 + ct * 16 + l16;
        float bias = b1[n];
#pragma unroll
        for (int r = 0; r < 4; ++r)
            sm[(rbase + r) * 260 + n] = acc[ct][r] + bias;
    }
    __syncthreads();
    const int row = t >> 4, sub = t & 15;
    float s1 = 0.f, s2 = 0.f;
#pragma unroll
    for (int i = 0; i < 16; ++i) {
        float v = sm[row * 260 + sub + 16 * i];
        s1 += v; s2 += v * v;
    }
#pragma unroll
    for (int off = 8; off; off >>= 1) {
        s1 += __shfl_xor(s1, off, 16);
        s2 += __shfl_xor(s2, off, 16);
    }
    float mu = s1 * (1.0f / 256.0f);
    float var = s2 * (1.0f / 256.0f) - mu * mu;
    float rstd = rsqrtf(var + EPSV);
#pragma unroll
    for (int i = 0; i < 16; ++i) {
        int cc = sub + 16 * i;
        float v = sm[row * 260 + cc];
        float xn = (v - mu) * rstd * lng[cc] + lnb[cc];
        float ge = 0.5f * xn * (1.0f + erff(xn * 0.7071067811865475f));
        qg[(size_t)(q0 + row) * 256 + cc] = f2bf(ge);
    }
}

// ---------------- GEMM2 (2048x256x256) + bias + Poincare project -> qb bf16, x2 ----------------
__global__ __launch_bounds__(256) void k_g2(const u16* __restrict__ qg,
                                            const u16* __restrict__ w2t,
                                            const float* __restrict__ b2,
                                            u16* __restrict__ qbb,
                                            float* __restrict__ x2q) {
    __shared__ float sm[16 * 260];
    const int t = threadIdx.x;
    const int w = t >> 6, lane = t & 63;
    const int l16 = lane & 15, kq = (lane >> 4) * 8, rbase = (lane >> 4) * 4;
    const int q0 = blockIdx.x * 16;
    f32x4 zero = {0.f, 0.f, 0.f, 0.f};
    f32x4 acc[4] = {zero, zero, zero, zero};
    const u16* ap = qg + (size_t)(q0 + l16) * 256 + kq;
    for (int k0 = 0; k0 < 256; k0 += 32) {
        short8 av = *(const short8*)(ap + k0);
#pragma unroll
        for (int ct = 0; ct < 4; ++ct) {
            int n = w * 64 + ct * 16 + l16;
            short8 bv = *(const short8*)&w2t[(size_t)n * 256 + k0 + kq];
            acc[ct] = __builtin_amdgcn_mfma_f32_16x16x32_bf16(av, bv, acc[ct], 0, 0, 0);
        }
    }
#pragma unroll
    for (int ct = 0; ct < 4; ++ct) {
        int n = w * 64 + ct * 16 + l16;
        float bias = b2[n];
#pragma unroll
        for (int r = 0; r < 4; ++r)
            sm[(rbase + r) * 260 + n] = acc[ct][r] + bias;
    }
    __syncthreads();
    const int row = t >> 4, sub = t & 15;
    float s2 = 0.f;
#pragma unroll
    for (int i = 0; i < 16; ++i) {
        float v = sm[row * 260 + sub + 16 * i];
        s2 += v * v;
    }
#pragma unroll
    for (int off = 8; off; off >>= 1) s2 += __shfl_xor(s2, off, 16);
    float norm = sqrtf(s2);
    float scale = (norm > MAXN) ? MAXN / fmaxf(norm, EPSV) : 1.0f;
    if (sub == 0) x2q[q0 + row] = s2 * scale * scale;
#pragma unroll
    for (int i = 0; i < 16; ++i) {
        int cc = sub + 16 * i;
        qbb[(size_t)(q0 + row) * 256 + cc] = f2bf(sm[row * 260 + cc] * scale);
    }
}

// ---------------- main: dot products via MFMA + threshold candidate collection ----------------
// grid 1024: qt = (b>>3)&31 (64 queries each), sl = (b&7)|((b>>8)<<3) (2048 mem rows each)
#define QS_STRIDE 264
__global__ __launch_bounds__(256, 3) void k_dist(const u16* __restrict__ qb,
                                                 const u16* __restrict__ mbf,
                                                 u32* __restrict__ cnt,
                                                 uint2* __restrict__ cand) {
    __shared__ u16 qs[64 * QS_STRIDE];
    const int b = blockIdx.x;
    const int sl = (b & 7) | ((b >> 8) << 3);
    const int qt = (b >> 3) & 31;
    const int t = threadIdx.x;
    {
        const u16* src = qb + (size_t)qt * 64 * 256;
        for (int i = 0; i < 8; ++i) {
            int seg = i * 256 + t;
            int row = seg >> 5, s = (seg & 31) * 8;
            *(short8*)&qs[row * QS_STRIDE + s] = *(const short8*)&src[row * 256 + s];
        }
    }
    __syncthreads();
    const int w = t >> 6, lane = t & 63;
    const int l16 = lane & 15, kq = (lane >> 4) * 8, rbase = (lane >> 4) * 4;
    f32x4 zero = {0.f, 0.f, 0.f, 0.f};
    for (int g = 0; g < 8; ++g) {
        const int mbase = sl * 2048 + (g * 4 + w) * 64;
        const u16* mp = mbf + (size_t)mbase * 256;
        f32x4 acc[4][4];
#pragma unroll
        for (int i = 0; i < 4; ++i)
#pragma unroll
            for (int j = 0; j < 4; ++j) acc[i][j] = zero;
        for (int k0 = 0; k0 < 256; k0 += 32) {
            short8 av[4], bv[4];
#pragma unroll
            for (int rt = 0; rt < 4; ++rt)
                av[rt] = *(const short8*)&qs[(rt * 16 + l16) * QS_STRIDE + k0 + kq];
#pragma unroll
            for (int ct = 0; ct < 4; ++ct)
                bv[ct] = *(const short8*)&mp[(size_t)(ct * 16 + l16) * 256 + k0 + kq];
#pragma unroll
            for (int rt = 0; rt < 4; ++rt)
#pragma unroll
                for (int ct = 0; ct < 4; ++ct)
                    acc[rt][ct] = __builtin_amdgcn_mfma_f32_16x16x32_bf16(av[rt], bv[ct], acc[rt][ct], 0, 0, 0);
        }
#pragma unroll
        for (int rt = 0; rt < 4; ++rt)
#pragma unroll
            for (int ct = 0; ct < 4; ++ct)
#pragma unroll
                for (int r = 0; r < 4; ++r) {
                    float d = acc[rt][ct][r];
                    if (d > THETA) {
                        int q = qt * 64 + rt * 16 + rbase + r;
                        int m = mbase + ct * 16 + l16;
                        u32 pos = atomicAdd(&cnt[q], 1u);
                        if (pos < CAP) cand[(size_t)q * CAP + pos] = make_uint2((u32)m, __float_as_uint(d));
                    }
                }
    }
}

// ---------------- merge: exact top-16, softmax(-dist), weighted gather -> rb bf16 ----------------
__global__ __launch_bounds__(64, 4) void k_merge(const u32* __restrict__ cnt,
                                                 const uint2* __restrict__ cand,
                                                 const float* __restrict__ x2q,
                                                 const float* __restrict__ y2m,
                                                 const u16* __restrict__ mbf,
                                                 u16* __restrict__ rb) {
    const int q = blockIdx.x;
    const int lane = threadIdx.x;
    int n = (int)cnt[q]; if (n > CAP) n = CAP;
    const float x2 = x2q[q];
    const float dx = 1.0f - x2;
    float rv[8]; u32 mi[8];
#pragma unroll
    for (int j = 0; j < 8; ++j) {
        int idx = lane + 64 * j;
        rv[j] = 3.0e38f; mi[j] = 0;
        if (idx < n) {
            uint2 c = cand[(size_t)q * CAP + idx];
            float dot = __uint_as_float(c.y);
            float y2 = y2m[c.x];
            float sq = fmaxf(x2 + y2 - 2.0f * dot, 0.0f);
            float den = fmaxf(dx * (1.0f - y2), EPSV);
            rv[j] = sq / den;
            mi[j] = c.x;
        }
    }
    __shared__ float sdist[16];
    __shared__ u32 smi[16];
    __shared__ float swt[16];
    for (int k = 0; k < 16; ++k) {
        float lm = rv[0]; int ls = 0;
#pragma unroll
        for (int j = 1; j < 8; ++j) if (rv[j] < lm) { lm = rv[j]; ls = j; }
        unsigned long long key = (((unsigned long long)__float_as_uint(lm)) << 32) | (u32)(lane * 8 + ls);
#pragma unroll
        for (int off = 32; off; off >>= 1) {
            unsigned long long o = __shfl_xor(key, off);
            key = (o < key) ? o : key;
        }
        u32 sid = (u32)(key & 0xffffffffu);
        int wl = (int)(sid >> 3), wslot = (int)(sid & 7);
        if (lane == wl) {
            sdist[k] = rv[wslot];
            smi[k] = mi[wslot];
            rv[wslot] = 3.0e38f;
        }
    }
    __syncthreads();
    float rr = sdist[lane & 15];
    float arg = fmaxf(fmaf(2.0f, rr, 1.0f), 1.0f + EPSV);
    float dneg = -acoshf(arg);
    float mx = dneg;
#pragma unroll
    for (int off = 8; off; off >>= 1) mx = fmaxf(mx, __shfl_xor(mx, off, 16));
    float e = expf(dneg - mx);
    float ssum = e;
#pragma unroll
    for (int off = 8; off; off >>= 1) ssum += __shfl_xor(ssum, off, 16);
    if (lane < 16) swt[lane] = e / ssum;
    __syncthreads();
    float acc[4] = {0.f, 0.f, 0.f, 0.f};
    for (int k = 0; k < 16; ++k) {
        float wk = swt[k];
        const u16* mr = mbf + (size_t)smi[k] * 256;
#pragma unroll
        for (int j = 0; j < 4; ++j) acc[j] += wk * bf2f(mr[lane + 64 * j]);
    }
#pragma unroll
    for (int j = 0; j < 4; ++j) rb[(size_t)q * 256 + lane + 64 * j] = f2bf(acc[j]);
}

// ---------------- output: out = hidden + 0.1*(rb @ wp + bp) ----------------
// grid 512: mt = b&31 (64 rows), nt = b>>5 (64 cols); wave w: cols [nt*64+w*16, +16)
__global__ __launch_bounds__(256) void k_out(const u16* __restrict__ rb,
                                             const u16* __restrict__ wpt,
                                             const float* __restrict__ bp,
                                             const float* __restrict__ hidden,
                                             float* __restrict__ out) {
    const int b = blockIdx.x;
    const int mt = b & 31, nt = b >> 5;
    const int t = threadIdx.x;
    const int w = t >> 6, lane = t & 63;
    const int l16 = lane & 15, kq = (lane >> 4) * 8, rbase = (lane >> 4) * 4;
    const int n = nt * 64 + w * 16 + l16;
    f32x4 zero = {0.f, 0.f, 0.f, 0.f};
    f32x4 acc[4] = {zero, zero, zero, zero};
    for (int k0 = 0; k0 < 256; k0 += 32) {
        short8 bv = *(const short8*)&wpt[(size_t)n * 256 + k0 + kq];
#pragma unroll
        for (int rt = 0; rt < 4; ++rt) {
            short8 av = *(const short8*)&rb[(size_t)(mt * 64 + rt * 16 + l16) * 256 + k0 + kq];
            acc[rt] = __builtin_amdgcn_mfma_f32_16x16x32_bf16(av, bv, acc[rt], 0, 0, 0);
        }
    }
    float bpn = bp[n];
#pragma unroll
    for (int rt = 0; rt < 4; ++rt)
#pragma unroll
        for (int r = 0; r < 4; ++r) {
            int m = mt * 64 + rt * 16 + rbase + r;
            out[(size_t)m * 1024 + n] = hidden[(size_t)m * 1024 + n] + 0.1f * (acc[rt][r] + bpn);
        }
}

extern "C" void kernel_launch(void* const* d_in, const int* in_sizes, int n_in,
                              void* d_out, int out_size, void* d_ws, size_t ws_size,
                              hipStream_t stream) {
    const float* hidden = (const float*)d_in[0];
    const float* memory = (const float*)d_in[1];
    const float* w1 = (const float*)d_in[2];
    const float* b1 = (const float*)d_in[3];
    const float* ln_g = (const float*)d_in[4];
    const float* ln_b = (const float*)d_in[5];
    const float* w2 = (const float*)d_in[6];
    const float* b2 = (const float*)d_in[7];
    const float* wp = (const float*)d_in[8];
    const float* bp = (const float*)d_in[9];
    float* out = (float*)d_out;
    char* ws = (char*)d_ws;

    u16* mbf  = (u16*)(ws);                       // 65536*256*2 = 33554432
    float* y2m = (float*)(ws + 33554432);         // 262144
    u16* hb   = (u16*)(ws + 33816576);            // 2048*1024*2 = 4194304
    u16* w1t  = (u16*)(ws + 38010880);            // 524288
    u16* w2t  = (u16*)(ws + 38535168);            // 131072
    u16* wpt  = (u16*)(ws + 38666240);            // 524288
    u16* qg   = (u16*)(ws + 39190528);            // 1048576
    u16* qbb  = (u16*)(ws + 40239104);            // 1048576
    float* x2q = (float*)(ws + 41287680);         // 8192
    u32* cnt  = (u32*)(ws + 41295872);            // 8192
    uint2* cand = (uint2*)(ws + 41304064);        // 2048*512*8 = 8388608
    u16* rb   = (u16*)(ws + 49692672);            // 1048576

    hipLaunchKernelGGL(k_zero, dim3(8), dim3(256), 0, stream, cnt, 2048);
    hipLaunchKernelGGL(k_mem, dim3(16384), dim3(256), 0, stream, memory, mbf, y2m);
    hipLaunchKernelGGL(k_conv4, dim3(2048), dim3(256), 0, stream, hidden, hb, 2048 * 1024 / 4);
    hipLaunchKernelGGL(k_tr, dim3(1024), dim3(256), 0, stream, w1, w1t, 1024, 256);
    hipLaunchKernelGGL(k_tr, dim3(256), dim3(256), 0, stream, w2, w2t, 256, 256);
    hipLaunchKernelGGL(k_tr, dim3(1024), dim3(256), 0, stream, wp, wpt, 256, 1024);
    hipLaunchKernelGGL(k_g1, dim3(128), dim3(256), 0, stream, hb, w1t, b1, ln_g, ln_b, qg);
    hipLaunchKernelGGL(k_g2, dim3(128), dim3(256), 0, stream, qg, w2t, b2, qbb, x2q);
    hipLaunchKernelGGL(k_dist, dim3(1024), dim3(256), 0, stream, qbb, mbf, cnt, cand);
    hipLaunchKernelGGL(k_merge, dim3(2048), dim3(64), 0, stream, cnt, cand, x2q, y2m, mbf, rb);
    hipLaunchKernelGGL(k_out, dim3(512), dim3(256), 0, stream, rb, wpt, bp, hidden, out);
}